// Round 4
// baseline (1467.422 us; speedup 1.0000x reference)
//
#include <hip/hip_runtime.h>
#include <cstdint>
#include <cstddef>

#define Vv 32000
#define Ee 256
#define Hh 256
#define Bb 4
#define Tt 512
#define Mm (Bb*Tt)   // 2048

typedef unsigned int u32;
typedef unsigned short u16;
typedef unsigned long long u64;
typedef __bf16 bf16x8 __attribute__((ext_vector_type(8)));
typedef float f32x4 __attribute__((ext_vector_type(4)));

__device__ __forceinline__ u16 f2bf(float f) {
  u32 u = __float_as_uint(f);
  u32 r = (u + 0x7FFFu + ((u >> 16) & 1u)) >> 16;   // RNE
  return (u16)r;
}

// ---------------------------------------------------------------------------
// Small GEMM: C[M,N] = A[M,256] @ W[N,256]^T + bias (A optionally gathered).
// ---------------------------------------------------------------------------
template<bool GATHER>
__global__ __launch_bounds__(256) void gemm_small(
    const float* __restrict__ A, const int* __restrict__ xidx,
    const float* __restrict__ W, const float* __restrict__ bias,
    float* __restrict__ C, int N)
{
  __shared__ float At[64][36];
  __shared__ float Wt[64][66];
  const int tid = threadIdx.x;
  const int m0 = blockIdx.x * 32;
  const int n0 = blockIdx.y * 64;
  const int tm = tid >> 5;
  const int tn = tid & 31;
  float acc[4][2] = {};

  for (int k0 = 0; k0 < 256; k0 += 64) {
    __syncthreads();
    #pragma unroll
    for (int r = 0; r < 2; ++r) {
      int idx = tid + r*256;
      int i  = idx >> 4;
      int c4 = idx & 15;
      const float* src;
      if (GATHER) src = A + (size_t)xidx[m0+i]*256 + k0 + c4*4;
      else        src = A + (size_t)(m0+i)*256 + k0 + c4*4;
      float4 v = *(const float4*)src;
      At[c4*4+0][i]=v.x; At[c4*4+1][i]=v.y; At[c4*4+2][i]=v.z; At[c4*4+3][i]=v.w;
    }
    #pragma unroll
    for (int r = 0; r < 4; ++r) {
      int idx = tid + r*256;
      int j  = idx >> 4;
      int c4 = idx & 15;
      float4 v = *(const float4*)(W + (size_t)(n0+j)*256 + k0 + c4*4);
      Wt[c4*4+0][j]=v.x; Wt[c4*4+1][j]=v.y; Wt[c4*4+2][j]=v.z; Wt[c4*4+3][j]=v.w;
    }
    __syncthreads();
    #pragma unroll 8
    for (int k = 0; k < 64; ++k) {
      float4 a = *(const float4*)&At[k][tm*4];
      float2 w = *(const float2*)&Wt[k][tn*2];
      acc[0][0] += a.x*w.x; acc[0][1] += a.x*w.y;
      acc[1][0] += a.y*w.x; acc[1][1] += a.y*w.y;
      acc[2][0] += a.z*w.x; acc[2][1] += a.z*w.y;
      acc[3][0] += a.w*w.x; acc[3][1] += a.w*w.y;
    }
  }
  #pragma unroll
  for (int i = 0; i < 4; ++i)
    #pragma unroll
    for (int j = 0; j < 2; ++j) {
      int m = m0 + tm*4 + i, n = n0 + tn*2 + j;
      C[(size_t)m*N + n] = acc[i][j] + bias[n];
    }
}

// ---------------------------------------------------------------------------
// GRU scan v5.
//  - grid 64 x 768 threads. (bid&7)<4: scan, batch=bid&7 (XCD-colocated under
//    round-robin mapping), chunk c=bid>>3 owns rows {g*256+c*32+j}.
//  - thread = (row r = tid>>3, k-group g = tid&7): 32 weights/thread in
//    registers (small enough that the allocator keeps them; round-3 showed
//    128/thread spills to scratch, VGPR stuck at 88).
//  - row dot = 8 f32x4 FMA + 3 shfl_xor (g = lane low bits).
//  - handoff: 256 threads poll one self-validating (float,tag) u64 pair each.
//  - (bid&7)>=4: fused fcW->bf16 conversion, overlapped with the scan.
// ---------------------------------------------------------------------------
__global__ __launch_bounds__(768, 1) void gru_scan(
    const float* __restrict__ xp, const float* __restrict__ h0,
    const float* __restrict__ whh, const float* __restrict__ bhh,
    float* __restrict__ gout, u64* __restrict__ hpair,
    const float* __restrict__ fcW, u16* __restrict__ Wb)
{
  const int tid = threadIdx.x;
  const int bid = blockIdx.x;
  const int b = bid & 7;     // batch (live if <4) -> XCD color
  const int c = bid >> 3;    // j-chunk (32 j's)

  if (b >= 4) {
    // ---- fused fcW -> bf16 conversion on the idle XCDs ----
    const int cbid = (c << 2) | (b - 4);          // 0..31
    const int n8 = Vv*512/8;                      // 2,048,000 groups of 8
    for (int i = cbid*768 + tid; i < n8; i += 32*768) {
      float4 a = ((const float4*)fcW)[i*2];
      float4 v = ((const float4*)fcW)[i*2+1];
      uint4 o;
      o.x = (u32)f2bf(a.x) | ((u32)f2bf(a.y) << 16);
      o.y = (u32)f2bf(a.z) | ((u32)f2bf(a.w) << 16);
      o.z = (u32)f2bf(v.x) | ((u32)f2bf(v.y) << 16);
      o.w = (u32)f2bf(v.z) | ((u32)f2bf(v.w) << 16);
      ((uint4*)Wb)[i] = o;
    }
    return;
  }

  __shared__ __attribute__((aligned(16))) float hl[256];
  __shared__ float dl[96];

  const int r = tid >> 3;    // 0..95 : row within chunk (gate*32 + j)
  const int g = tid & 7;     // k-group (32 k's)
  const int grow = (r >> 5)*256 + c*32 + (r & 31);

  // --- 32 weights into registers (8 x float4 load, scalarized + pinned)
  float w[32];
  {
    const float4* wp = (const float4*)(whh + (size_t)grow*256 + g*32);
    #pragma unroll
    for (int kk = 0; kk < 8; ++kk) {
      float4 v = wp[kk];
      w[4*kk+0] = v.x; w[4*kk+1] = v.y; w[4*kk+2] = v.z; w[4*kk+3] = v.w;
    }
  }
  #pragma unroll
  for (int kk = 0; kk < 32; ++kk) asm volatile("" : "+v"(w[kk]));

  float b_r = 0.f, b_z = 0.f, b_n = 0.f;
  const int jg = c*32 + (tid & 31);
  if (tid < 32) { b_r = bhh[jg]; b_z = bhh[256+jg]; b_n = bhh[512+jg]; }

  for (int t = 0; t < Tt; ++t) {
    // prefetch xp for gate threads (issues before the poll; hides L2 latency)
    float xr = 0.f, xz = 0.f, xn = 0.f;
    if (tid < 32) {
      size_t xb = ((size_t)(b*Tt) + t)*768 + jg;
      xr = xp[xb]; xz = xp[xb+256]; xn = xp[xb+512];
    }

    // --- acquire h_{t-1}: each of 256 threads polls ONE (value,tag) pair
    if (tid < 256) {
      float hv;
      if (t == 0) {
        hv = h0[b*Hh + tid];
      } else {
        const u64* src = hpair + ((size_t)(b*2) + ((t-1)&1))*256 + tid;
        const u32 want = (u32)t;           // tag of h after step t-1
        u64 v;
        do {
          v = __hip_atomic_load(src, __ATOMIC_RELAXED, __HIP_MEMORY_SCOPE_AGENT);
        } while ((u32)(v >> 32) != want);
        hv = __uint_as_float((u32)v);
      }
      hl[tid] = hv;
    }
    __syncthreads();

    // --- dot: thread (r,g) covers k in [g*32, g*32+32); h reads are 8-lane
    //     same-address broadcasts (conflict-free); weights in VGPRs
    float s0 = 0.f, s1 = 0.f, s2 = 0.f, s3 = 0.f;
    {
      const float* hp = &hl[g*32];
      #pragma unroll
      for (int kk = 0; kk < 8; ++kk) {
        float4 h4 = *(const float4*)(hp + kk*4);
        s0 += w[4*kk+0]*h4.x;
        s1 += w[4*kk+1]*h4.y;
        s2 += w[4*kk+2]*h4.z;
        s3 += w[4*kk+3]*h4.w;
      }
    }
    float s = (s0 + s1) + (s2 + s3);
    s += __shfl_xor(s, 1);
    s += __shfl_xor(s, 2);
    s += __shfl_xor(s, 4);
    if (g == 0) dl[r] = s;
    __syncthreads();

    // --- gates + handoff store (pair store FIRST: it's the critical edge)
    if (tid < 32) {
      int j = tid;
      float dr = dl[j], dz = dl[32+j], dn = dl[64+j];
      float rr = 1.f/(1.f + __expf(-(xr + dr + b_r)));
      float zz = 1.f/(1.f + __expf(-(xz + dz + b_z)));
      float aa = xn + rr*(dn + b_n);
      float nn = 1.f - 2.f/(1.f + __expf(2.f*aa));     // tanh
      float hp = hl[jg];
      float hn = (1.f - zz)*nn + zz*hp;
      u64 pv = ((u64)(u32)(t + 1) << 32) | (u64)__float_as_uint(hn);
      __hip_atomic_store(hpair + ((size_t)(b*2) + (t&1))*256 + jg, pv,
                         __ATOMIC_RELAXED, __HIP_MEMORY_SCOPE_AGENT);
      gout[((size_t)(b*Tt) + t)*Hh + jg] = hn;
    }
  }
}

// ---------------------------------------------------------------------------
// Attention (unchanged)
// ---------------------------------------------------------------------------
__global__ __launch_bounds__(256) void attn_kernel(
    const float* __restrict__ outm, const float* __restrict__ qm,
    const float* __restrict__ km, const float* __restrict__ vW,
    const float* __restrict__ vb_p, float* __restrict__ ctx)
{
  __shared__ __attribute__((aligned(16))) float q[256];
  __shared__ __attribute__((aligned(16))) float vv[256];
  __shared__ float p[512];
  __shared__ float red[8];

  const int blk = blockIdx.x;
  const int b = blk >> 9;
  const int i = 511 - (blk & 511);
  const int tid = threadIdx.x;

  if (tid < 64) {
    ((float4*)q)[tid]  = ((const float4*)(qm + ((size_t)(b*Tt)+i)*Hh))[tid];
    ((float4*)vv)[tid] = ((const float4*)vW)[tid];
  }
  const float vb = vb_p[0];
  __syncthreads();

  for (int j = tid; j <= i; j += 256) {
    const float* kr = km + ((size_t)(b*Tt)+j)*Hh;
    float s = 0.f;
    #pragma unroll 4
    for (int h = 0; h < 256; h += 4) {
      float4 kv = *(const float4*)(kr + h);
      float x0 = q[h+0]+kv.x, x1 = q[h+1]+kv.y, x2 = q[h+2]+kv.z, x3 = q[h+3]+kv.w;
      s += vv[h+0]*(1.f - 2.f/(1.f + __expf(2.f*x0)));
      s += vv[h+1]*(1.f - 2.f/(1.f + __expf(2.f*x1)));
      s += vv[h+2]*(1.f - 2.f/(1.f + __expf(2.f*x2)));
      s += vv[h+3]*(1.f - 2.f/(1.f + __expf(2.f*x3)));
    }
    p[j] = s + vb;
  }
  __syncthreads();

  float m = -1e30f;
  for (int j = tid; j <= i; j += 256) m = fmaxf(m, p[j]);
  #pragma unroll
  for (int off = 32; off; off >>= 1) m = fmaxf(m, __shfl_xor(m, off));
  if ((tid & 63) == 0) red[tid >> 6] = m;
  __syncthreads();
  m = fmaxf(fmaxf(red[0], red[1]), fmaxf(red[2], red[3]));

  float s = 0.f;
  for (int j = tid; j <= i; j += 256) { float e = __expf(p[j]-m); p[j] = e; s += e; }
  #pragma unroll
  for (int off = 32; off; off >>= 1) s += __shfl_xor(s, off);
  if ((tid & 63) == 0) red[4 + (tid >> 6)] = s;
  __syncthreads();
  s = red[4]+red[5]+red[6]+red[7];
  const float inv = 1.f/s;

  float acc = 0.f;
  const float* op = outm + (size_t)(b*Tt)*Hh + tid;
  #pragma unroll 4
  for (int j = 0; j <= i; ++j) acc += p[j] * op[(size_t)j*Hh];
  ctx[((size_t)(b*Tt)+i)*Hh + tid] = acc*inv;
}

__global__ __launch_bounds__(256) void conv_comb_bf16(
    const float* __restrict__ gout, const float* __restrict__ ctx,
    u16* __restrict__ dst)
{
  int i = blockIdx.x*256 + threadIdx.x;     // 131072 groups of 8
  int m  = i >> 6;
  int kg = (i & 63) * 8;
  const float* src = (kg < 256) ? (gout + (size_t)m*256 + kg)
                                : (ctx  + (size_t)m*256 + kg - 256);
  float4 a = *(const float4*)src;
  float4 b = *(const float4*)(src + 4);
  uint4 o;
  o.x = (u32)f2bf(a.x) | ((u32)f2bf(a.y) << 16);
  o.y = (u32)f2bf(a.z) | ((u32)f2bf(a.w) << 16);
  o.z = (u32)f2bf(b.x) | ((u32)f2bf(b.y) << 16);
  o.w = (u32)f2bf(b.z) | ((u32)f2bf(b.w) << 16);
  ((uint4*)dst)[i] = o;
}

// ---------------------------------------------------------------------------
// FC MFMA: logits[2048,32000] = comb_bf16 @ Wb^T + fc_b. (unchanged)
// ---------------------------------------------------------------------------
__global__ __launch_bounds__(256) void fc_mfma(
    const u16* __restrict__ Ab, const u16* __restrict__ Wb,
    const float* __restrict__ bias, float* __restrict__ C)
{
  __shared__ __attribute__((aligned(16))) u16 As[128*32];
  __shared__ __attribute__((aligned(16))) u16 Bs[128*32];
  const int bid = blockIdx.x;
  const int mt = bid & 15, nt = bid >> 4;
  const int m0 = mt*128, n0 = nt*128;
  const int tid = threadIdx.x;
  const int wave = tid >> 6, lane = tid & 63;

  f32x4 acc[4][4];
  #pragma unroll
  for (int i = 0; i < 4; ++i)
    #pragma unroll
    for (int j = 0; j < 4; ++j)
      acc[i][j] = (f32x4){0.f, 0.f, 0.f, 0.f};

  const int wm = (wave & 1)*64;
  const int wn = (wave >> 1)*64;
  const int frow = lane & 15;
  const int fk   = (lane >> 4)*8;

  for (int k0 = 0; k0 < 512; k0 += 32) {
    __syncthreads();
    #pragma unroll
    for (int i = 0; i < 2; ++i) {
      int ebase = wave*1024 + i*512;
      int e = ebase + lane*8;
      int row = e >> 5, col = e & 31;
      __builtin_amdgcn_global_load_lds(
          (const __attribute__((address_space(1))) u32*)(Ab + (size_t)(m0+row)*512 + k0 + col),
          (__attribute__((address_space(3))) u32*)(As + ebase), 16, 0, 0);
      __builtin_amdgcn_global_load_lds(
          (const __attribute__((address_space(1))) u32*)(Wb + (size_t)(n0+row)*512 + k0 + col),
          (__attribute__((address_space(3))) u32*)(Bs + ebase), 16, 0, 0);
    }
    __syncthreads();

    bf16x8 af[4], bfr[4];
    #pragma unroll
    for (int mi = 0; mi < 4; ++mi)
      af[mi] = *(const bf16x8*)&As[(wm + mi*16 + frow)*32 + fk];
    #pragma unroll
    for (int ni = 0; ni < 4; ++ni)
      bfr[ni] = *(const bf16x8*)&Bs[(wn + ni*16 + frow)*32 + fk];
    #pragma unroll
    for (int mi = 0; mi < 4; ++mi)
      #pragma unroll
      for (int ni = 0; ni < 4; ++ni)
        acc[mi][ni] = __builtin_amdgcn_mfma_f32_16x16x32_bf16(af[mi], bfr[ni], acc[mi][ni], 0, 0, 0);
  }

  const int coln = lane & 15, rq = (lane >> 4)*4;
  #pragma unroll
  for (int ni = 0; ni < 4; ++ni) {
    int n = n0 + wn + ni*16 + coln;
    float bb = bias[n];
    #pragma unroll
    for (int mi = 0; mi < 4; ++mi) {
      int mbase = m0 + wm + mi*16 + rq;
      #pragma unroll
      for (int r2 = 0; r2 < 4; ++r2)
        C[(size_t)(mbase + r2)*Vv + n] = acc[mi][ni][r2] + bb;
    }
  }
}

__global__ void copy_hlast(const float* __restrict__ gout, float* __restrict__ dst)
{
  int idx = blockIdx.x*256 + threadIdx.x;
  if (idx < Bb*Hh) {
    int b = idx >> 8, h = idx & 255;
    dst[idx] = gout[((size_t)(b*Tt) + (Tt-1))*Hh + h];
  }
}

extern "C" void kernel_launch(void* const* d_in, const int* in_sizes, int n_in,
                              void* d_out, int out_size, void* d_ws, size_t ws_size,
                              hipStream_t stream)
{
  const int*   x    = (const int*)  d_in[0];
  const float* h0   = (const float*)d_in[1];
  const float* embW = (const float*)d_in[2];
  const float* wih  = (const float*)d_in[3];
  const float* bih  = (const float*)d_in[4];
  const float* whh  = (const float*)d_in[5];
  const float* bhh  = (const float*)d_in[6];
  const float* awW  = (const float*)d_in[7];
  const float* awb  = (const float*)d_in[8];
  const float* auW  = (const float*)d_in[9];
  const float* aub  = (const float*)d_in[10];
  const float* avW  = (const float*)d_in[11];
  const float* avb  = (const float*)d_in[12];
  const float* fcW  = (const float*)d_in[13];
  const float* fcb  = (const float*)d_in[14];
  float* outp = (float*)d_out;

  float* ws   = (float*)d_ws;
  float* xp   = ws;                                  // 2048*768
  float* gout = xp   + (size_t)Mm*768;               // 2048*256
  float* q    = gout + (size_t)Mm*Hh;
  float* k    = q    + (size_t)Mm*Hh;
  float* ctx  = k    + (size_t)Mm*Hh;
  u64*  hpair = (u64*)(ctx + (size_t)Mm*Hh);         // 4*2*256 pairs = 16 KB
  u16* comb = (u16*)(hpair + 2048);                  // 2048*512 bf16
  u16* Wb   = comb + (size_t)Mm*512;                 // 32000*512 bf16

  dim3 g1(Mm/32, 768/64);
  gemm_small<true><<<g1, 256, 0, stream>>>(embW, x, wih, bih, xp, 768);

  // gru_scan also performs the fcW->bf16 conversion on its idle blocks
  gru_scan<<<64, 768, 0, stream>>>(xp, h0, whh, bhh, gout, hpair, fcW, Wb);

  dim3 g3(Mm/32, 256/64);
  gemm_small<false><<<g3, 256, 0, stream>>>(gout, nullptr, awW, awb, q, 256);
  gemm_small<false><<<g3, 256, 0, stream>>>(gout, nullptr, auW, aub, k, 256);

  attn_kernel<<<Bb*Tt, 256, 0, stream>>>(gout, q, k, avW, avb, ctx);

  conv_comb_bf16<<<512, 256, 0, stream>>>(gout, ctx, comb);

  fc_mfma<<<16*250, 256, 0, stream>>>(comb, Wb, fcb, outp);

  copy_hlast<<<4, 256, 0, stream>>>(gout, outp + (size_t)Mm*Vv);
}

// Round 5
// 1261.899 us; speedup vs baseline: 1.1629x; 1.1629x over previous
//
#include <hip/hip_runtime.h>
#include <cstdint>
#include <cstddef>

#define Vv 32000
#define Ee 256
#define Hh 256
#define Bb 4
#define Tt 512
#define Mm (Bb*Tt)   // 2048

typedef unsigned int u32;
typedef unsigned short u16;
typedef unsigned long long u64;
typedef __bf16 bf16x8 __attribute__((ext_vector_type(8)));
typedef float f32x4 __attribute__((ext_vector_type(4)));

__device__ __forceinline__ u16 f2bf(float f) {
  u32 u = __float_as_uint(f);
  u32 r = (u + 0x7FFFu + ((u >> 16) & 1u)) >> 16;   // RNE
  return (u16)r;
}

// ---------------------------------------------------------------------------
// Small GEMM: C[M,N] = A[M,256] @ W[N,256]^T + bias (A optionally gathered).
// ---------------------------------------------------------------------------
template<bool GATHER>
__global__ __launch_bounds__(256) void gemm_small(
    const float* __restrict__ A, const int* __restrict__ xidx,
    const float* __restrict__ W, const float* __restrict__ bias,
    float* __restrict__ C, int N)
{
  __shared__ float At[64][36];
  __shared__ float Wt[64][66];
  const int tid = threadIdx.x;
  const int m0 = blockIdx.x * 32;
  const int n0 = blockIdx.y * 64;
  const int tm = tid >> 5;
  const int tn = tid & 31;
  float acc[4][2] = {};

  for (int k0 = 0; k0 < 256; k0 += 64) {
    __syncthreads();
    #pragma unroll
    for (int r = 0; r < 2; ++r) {
      int idx = tid + r*256;
      int i  = idx >> 4;
      int c4 = idx & 15;
      const float* src;
      if (GATHER) src = A + (size_t)xidx[m0+i]*256 + k0 + c4*4;
      else        src = A + (size_t)(m0+i)*256 + k0 + c4*4;
      float4 v = *(const float4*)src;
      At[c4*4+0][i]=v.x; At[c4*4+1][i]=v.y; At[c4*4+2][i]=v.z; At[c4*4+3][i]=v.w;
    }
    #pragma unroll
    for (int r = 0; r < 4; ++r) {
      int idx = tid + r*256;
      int j  = idx >> 4;
      int c4 = idx & 15;
      float4 v = *(const float4*)(W + (size_t)(n0+j)*256 + k0 + c4*4);
      Wt[c4*4+0][j]=v.x; Wt[c4*4+1][j]=v.y; Wt[c4*4+2][j]=v.z; Wt[c4*4+3][j]=v.w;
    }
    __syncthreads();
    #pragma unroll 8
    for (int k = 0; k < 64; ++k) {
      float4 a = *(const float4*)&At[k][tm*4];
      float2 w = *(const float2*)&Wt[k][tn*2];
      acc[0][0] += a.x*w.x; acc[0][1] += a.x*w.y;
      acc[1][0] += a.y*w.x; acc[1][1] += a.y*w.y;
      acc[2][0] += a.z*w.x; acc[2][1] += a.z*w.y;
      acc[3][0] += a.w*w.x; acc[3][1] += a.w*w.y;
    }
  }
  #pragma unroll
  for (int i = 0; i < 4; ++i)
    #pragma unroll
    for (int j = 0; j < 2; ++j) {
      int m = m0 + tm*4 + i, n = n0 + tn*2 + j;
      C[(size_t)m*N + n] = acc[i][j] + bias[n];
    }
}

// ---------------------------------------------------------------------------
// GRU scan v6: barrier-free steady state.
//  - 512 threads: thread (j=tid>>4, g=tid&15) owns rows {j, 32+j, 64+j} of
//    its chunk over k-slice {g*4 + 64m + i} (48 weights in regs; interleaved
//    k => conflict-free LDS h reads). shfl_xor over g gives lane g==0 all
//    three dots for j -> gates fully in-thread, no cross-wave exchange.
//  - wave0 is the only global poller: polls 256 (float,tag) u64 pairs
//    (agent scope, serviced at device coherence point), relays h into
//    hl[t&1] and release-stores an LDS tag; other waves acquire-spin on the
//    LDS tag (CU-local, cheap). NO __syncthreads in the loop.
//  - global hpair slots depth-4 (thread skew bound <= 2 via 2-step
//    transitive dependency closure); LDS h depth-2 (every wave contains a
//    gate lane => wave0 leads by at most 1 step).
//  - (bid&7)>=4 blocks do the fused fcW->bf16 conversion.
// ---------------------------------------------------------------------------
__global__ __launch_bounds__(512, 1) void gru_scan(
    const float* __restrict__ xp, const float* __restrict__ h0,
    const float* __restrict__ whh, const float* __restrict__ bhh,
    float* __restrict__ gout, u64* __restrict__ hpair,
    const float* __restrict__ fcW, u16* __restrict__ Wb)
{
  const int tid = threadIdx.x;
  const int bid = blockIdx.x;
  const int b = bid & 7;     // batch (live if <4) -> XCD color
  const int c = bid >> 3;    // j-chunk (32 j's)

  if (b >= 4) {
    // ---- fused fcW -> bf16 conversion on the idle XCDs ----
    const int cbid = (c << 2) | (b - 4);          // 0..31
    const int n8 = Vv*512/8;                      // 2,048,000 groups of 8
    for (int i = cbid*512 + tid; i < n8; i += 32*512) {
      float4 a = ((const float4*)fcW)[i*2];
      float4 v = ((const float4*)fcW)[i*2+1];
      uint4 o;
      o.x = (u32)f2bf(a.x) | ((u32)f2bf(a.y) << 16);
      o.y = (u32)f2bf(a.z) | ((u32)f2bf(a.w) << 16);
      o.z = (u32)f2bf(v.x) | ((u32)f2bf(v.y) << 16);
      o.w = (u32)f2bf(v.z) | ((u32)f2bf(v.w) << 16);
      ((uint4*)Wb)[i] = o;
    }
    return;
  }

  __shared__ __attribute__((aligned(16))) float hl[2][256];
  __shared__ u32 htag[2];

  const int j = tid >> 4;    // 0..31: gate row within chunk
  const int g = tid & 15;    // 0..15: k-slice

  if (tid < 2) htag[tid] = 0;
  __syncthreads();           // one-time (LDS tag init)

  // --- 48 weights (3 gates x 16 k) into registers, k = g*4 + 64m + i
  float w[48];
  {
    #pragma unroll
    for (int m = 0; m < 4; ++m) {
      float4 vr = *(const float4*)(whh + (size_t)(      c*32 + j)*256 + g*4 + 64*m);
      float4 vz = *(const float4*)(whh + (size_t)(256 + c*32 + j)*256 + g*4 + 64*m);
      float4 vn = *(const float4*)(whh + (size_t)(512 + c*32 + j)*256 + g*4 + 64*m);
      w[   m*4+0]=vr.x; w[   m*4+1]=vr.y; w[   m*4+2]=vr.z; w[   m*4+3]=vr.w;
      w[16+m*4+0]=vz.x; w[16+m*4+1]=vz.y; w[16+m*4+2]=vz.z; w[16+m*4+3]=vz.w;
      w[32+m*4+0]=vn.x; w[32+m*4+1]=vn.y; w[32+m*4+2]=vn.z; w[32+m*4+3]=vn.w;
    }
  }
  #pragma unroll
  for (int kk = 0; kk < 48; ++kk) asm volatile("" : "+v"(w[kk]));

  float b_r = 0.f, b_z = 0.f, b_n = 0.f, hprev = 0.f;
  if (g == 0) {
    b_r = bhh[c*32 + j]; b_z = bhh[256 + c*32 + j]; b_n = bhh[512 + c*32 + j];
    hprev = h0[b*Hh + c*32 + j];
  }

  for (int t = 0; t < Tt; ++t) {
    // xp prefetch for gate lanes (issues before any waiting)
    float xr = 0.f, xz = 0.f, xn = 0.f;
    if (g == 0) {
      size_t xb = ((size_t)(b*Tt) + t)*768 + c*32 + j;
      xr = xp[xb]; xz = xp[xb+256]; xn = xp[xb+512];
    }

    // --- wave0: global poll -> LDS relay
    if (tid < 64) {
      float4 hv;
      if (t == 0) {
        hv = *(const float4*)(h0 + b*Hh + tid*4);
      } else {
        const u64* src = hpair + ((size_t)(b*4) + ((t-1)&3))*256 + tid*4;
        const u32 want = (u32)t;           // tag of h after step t-1
        for (;;) {
          u64 v0 = __hip_atomic_load(src+0, __ATOMIC_RELAXED, __HIP_MEMORY_SCOPE_AGENT);
          u64 v1 = __hip_atomic_load(src+1, __ATOMIC_RELAXED, __HIP_MEMORY_SCOPE_AGENT);
          u64 v2 = __hip_atomic_load(src+2, __ATOMIC_RELAXED, __HIP_MEMORY_SCOPE_AGENT);
          u64 v3 = __hip_atomic_load(src+3, __ATOMIC_RELAXED, __HIP_MEMORY_SCOPE_AGENT);
          if (((u32)(v0 >> 32) == want) & ((u32)(v1 >> 32) == want) &
              ((u32)(v2 >> 32) == want) & ((u32)(v3 >> 32) == want)) {
            hv.x = __uint_as_float((u32)v0); hv.y = __uint_as_float((u32)v1);
            hv.z = __uint_as_float((u32)v2); hv.w = __uint_as_float((u32)v3);
            break;
          }
        }
      }
      *(float4*)&hl[t&1][tid*4] = hv;
      if (tid == 0)
        __hip_atomic_store(&htag[t&1], (u32)(t+1),
                           __ATOMIC_RELEASE, __HIP_MEMORY_SCOPE_WORKGROUP);
    }

    // --- all waves: spin on the LDS tag (CU-local)
    while (__hip_atomic_load(&htag[t&1], __ATOMIC_ACQUIRE,
                             __HIP_MEMORY_SCOPE_WORKGROUP) != (u32)(t+1)) {}

    // --- three dots over the k-slice (h reads conflict-free, 4-lane bcast)
    float sr = 0.f, sz = 0.f, sn = 0.f;
    #pragma unroll
    for (int m = 0; m < 4; ++m) {
      float4 h4 = *(const float4*)&hl[t&1][g*4 + 64*m];
      sr += w[   m*4+0]*h4.x + w[   m*4+1]*h4.y + w[   m*4+2]*h4.z + w[   m*4+3]*h4.w;
      sz += w[16+m*4+0]*h4.x + w[16+m*4+1]*h4.y + w[16+m*4+2]*h4.z + w[16+m*4+3]*h4.w;
      sn += w[32+m*4+0]*h4.x + w[32+m*4+1]*h4.y + w[32+m*4+2]*h4.z + w[32+m*4+3]*h4.w;
    }
    #pragma unroll
    for (int d = 1; d < 16; d <<= 1) {
      sr += __shfl_xor(sr, d);
      sz += __shfl_xor(sz, d);
      sn += __shfl_xor(sn, d);
    }

    // --- gates fully in-thread on lane g==0; store pair first (critical edge)
    if (g == 0) {
      float rr = 1.f/(1.f + __expf(-(xr + sr + b_r)));
      float zz = 1.f/(1.f + __expf(-(xz + sz + b_z)));
      float aa = xn + rr*(sn + b_n);
      float nn = 1.f - 2.f/(1.f + __expf(2.f*aa));     // tanh
      float hn = (1.f - zz)*nn + zz*hprev;
      u64 pv = ((u64)(u32)(t + 1) << 32) | (u64)__float_as_uint(hn);
      __hip_atomic_store(hpair + ((size_t)(b*4) + (t&3))*256 + c*32 + j, pv,
                         __ATOMIC_RELAXED, __HIP_MEMORY_SCOPE_AGENT);
      gout[((size_t)(b*Tt) + t)*Hh + c*32 + j] = hn;
      hprev = hn;
    }
  }
}

// ---------------------------------------------------------------------------
// Attention (unchanged)
// ---------------------------------------------------------------------------
__global__ __launch_bounds__(256) void attn_kernel(
    const float* __restrict__ outm, const float* __restrict__ qm,
    const float* __restrict__ km, const float* __restrict__ vW,
    const float* __restrict__ vb_p, float* __restrict__ ctx)
{
  __shared__ __attribute__((aligned(16))) float q[256];
  __shared__ __attribute__((aligned(16))) float vv[256];
  __shared__ float p[512];
  __shared__ float red[8];

  const int blk = blockIdx.x;
  const int b = blk >> 9;
  const int i = 511 - (blk & 511);
  const int tid = threadIdx.x;

  if (tid < 64) {
    ((float4*)q)[tid]  = ((const float4*)(qm + ((size_t)(b*Tt)+i)*Hh))[tid];
    ((float4*)vv)[tid] = ((const float4*)vW)[tid];
  }
  const float vb = vb_p[0];
  __syncthreads();

  for (int j = tid; j <= i; j += 256) {
    const float* kr = km + ((size_t)(b*Tt)+j)*Hh;
    float s = 0.f;
    #pragma unroll 4
    for (int h = 0; h < 256; h += 4) {
      float4 kv = *(const float4*)(kr + h);
      float x0 = q[h+0]+kv.x, x1 = q[h+1]+kv.y, x2 = q[h+2]+kv.z, x3 = q[h+3]+kv.w;
      s += vv[h+0]*(1.f - 2.f/(1.f + __expf(2.f*x0)));
      s += vv[h+1]*(1.f - 2.f/(1.f + __expf(2.f*x1)));
      s += vv[h+2]*(1.f - 2.f/(1.f + __expf(2.f*x2)));
      s += vv[h+3]*(1.f - 2.f/(1.f + __expf(2.f*x3)));
    }
    p[j] = s + vb;
  }
  __syncthreads();

  float m = -1e30f;
  for (int j = tid; j <= i; j += 256) m = fmaxf(m, p[j]);
  #pragma unroll
  for (int off = 32; off; off >>= 1) m = fmaxf(m, __shfl_xor(m, off));
  if ((tid & 63) == 0) red[tid >> 6] = m;
  __syncthreads();
  m = fmaxf(fmaxf(red[0], red[1]), fmaxf(red[2], red[3]));

  float s = 0.f;
  for (int j = tid; j <= i; j += 256) { float e = __expf(p[j]-m); p[j] = e; s += e; }
  #pragma unroll
  for (int off = 32; off; off >>= 1) s += __shfl_xor(s, off);
  if ((tid & 63) == 0) red[4 + (tid >> 6)] = s;
  __syncthreads();
  s = red[4]+red[5]+red[6]+red[7];
  const float inv = 1.f/s;

  float acc = 0.f;
  const float* op = outm + (size_t)(b*Tt)*Hh + tid;
  #pragma unroll 4
  for (int j = 0; j <= i; ++j) acc += p[j] * op[(size_t)j*Hh];
  ctx[((size_t)(b*Tt)+i)*Hh + tid] = acc*inv;
}

__global__ __launch_bounds__(256) void conv_comb_bf16(
    const float* __restrict__ gout, const float* __restrict__ ctx,
    u16* __restrict__ dst)
{
  int i = blockIdx.x*256 + threadIdx.x;     // 131072 groups of 8
  int m  = i >> 6;
  int kg = (i & 63) * 8;
  const float* src = (kg < 256) ? (gout + (size_t)m*256 + kg)
                                : (ctx  + (size_t)m*256 + kg - 256);
  float4 a = *(const float4*)src;
  float4 b = *(const float4*)(src + 4);
  uint4 o;
  o.x = (u32)f2bf(a.x) | ((u32)f2bf(a.y) << 16);
  o.y = (u32)f2bf(a.z) | ((u32)f2bf(a.w) << 16);
  o.z = (u32)f2bf(b.x) | ((u32)f2bf(b.y) << 16);
  o.w = (u32)f2bf(b.z) | ((u32)f2bf(b.w) << 16);
  ((uint4*)dst)[i] = o;
}

// ---------------------------------------------------------------------------
// FC MFMA: logits[2048,32000] = comb_bf16 @ Wb^T + fc_b. (unchanged)
// ---------------------------------------------------------------------------
__global__ __launch_bounds__(256) void fc_mfma(
    const u16* __restrict__ Ab, const u16* __restrict__ Wb,
    const float* __restrict__ bias, float* __restrict__ C)
{
  __shared__ __attribute__((aligned(16))) u16 As[128*32];
  __shared__ __attribute__((aligned(16))) u16 Bs[128*32];
  const int bid = blockIdx.x;
  const int mt = bid & 15, nt = bid >> 4;
  const int m0 = mt*128, n0 = nt*128;
  const int tid = threadIdx.x;
  const int wave = tid >> 6, lane = tid & 63;

  f32x4 acc[4][4];
  #pragma unroll
  for (int i = 0; i < 4; ++i)
    #pragma unroll
    for (int j = 0; j < 4; ++j)
      acc[i][j] = (f32x4){0.f, 0.f, 0.f, 0.f};

  const int wm = (wave & 1)*64;
  const int wn = (wave >> 1)*64;
  const int frow = lane & 15;
  const int fk   = (lane >> 4)*8;

  for (int k0 = 0; k0 < 512; k0 += 32) {
    __syncthreads();
    #pragma unroll
    for (int i = 0; i < 2; ++i) {
      int ebase = wave*1024 + i*512;
      int e = ebase + lane*8;
      int row = e >> 5, col = e & 31;
      __builtin_amdgcn_global_load_lds(
          (const __attribute__((address_space(1))) u32*)(Ab + (size_t)(m0+row)*512 + k0 + col),
          (__attribute__((address_space(3))) u32*)(As + ebase), 16, 0, 0);
      __builtin_amdgcn_global_load_lds(
          (const __attribute__((address_space(1))) u32*)(Wb + (size_t)(n0+row)*512 + k0 + col),
          (__attribute__((address_space(3))) u32*)(Bs + ebase), 16, 0, 0);
    }
    __syncthreads();

    bf16x8 af[4], bfr[4];
    #pragma unroll
    for (int mi = 0; mi < 4; ++mi)
      af[mi] = *(const bf16x8*)&As[(wm + mi*16 + frow)*32 + fk];
    #pragma unroll
    for (int ni = 0; ni < 4; ++ni)
      bfr[ni] = *(const bf16x8*)&Bs[(wn + ni*16 + frow)*32 + fk];
    #pragma unroll
    for (int mi = 0; mi < 4; ++mi)
      #pragma unroll
      for (int ni = 0; ni < 4; ++ni)
        acc[mi][ni] = __builtin_amdgcn_mfma_f32_16x16x32_bf16(af[mi], bfr[ni], acc[mi][ni], 0, 0, 0);
  }

  const int coln = lane & 15, rq = (lane >> 4)*4;
  #pragma unroll
  for (int ni = 0; ni < 4; ++ni) {
    int n = n0 + wn + ni*16 + coln;
    float bb = bias[n];
    #pragma unroll
    for (int mi = 0; mi < 4; ++mi) {
      int mbase = m0 + wm + mi*16 + rq;
      #pragma unroll
      for (int r2 = 0; r2 < 4; ++r2)
        C[(size_t)(mbase + r2)*Vv + n] = acc[mi][ni][r2] + bb;
    }
  }
}

__global__ void copy_hlast(const float* __restrict__ gout, float* __restrict__ dst)
{
  int idx = blockIdx.x*256 + threadIdx.x;
  if (idx < Bb*Hh) {
    int b = idx >> 8, h = idx & 255;
    dst[idx] = gout[((size_t)(b*Tt) + (Tt-1))*Hh + h];
  }
}

extern "C" void kernel_launch(void* const* d_in, const int* in_sizes, int n_in,
                              void* d_out, int out_size, void* d_ws, size_t ws_size,
                              hipStream_t stream)
{
  const int*   x    = (const int*)  d_in[0];
  const float* h0   = (const float*)d_in[1];
  const float* embW = (const float*)d_in[2];
  const float* wih  = (const float*)d_in[3];
  const float* bih  = (const float*)d_in[4];
  const float* whh  = (const float*)d_in[5];
  const float* bhh  = (const float*)d_in[6];
  const float* awW  = (const float*)d_in[7];
  const float* awb  = (const float*)d_in[8];
  const float* auW  = (const float*)d_in[9];
  const float* aub  = (const float*)d_in[10];
  const float* avW  = (const float*)d_in[11];
  const float* avb  = (const float*)d_in[12];
  const float* fcW  = (const float*)d_in[13];
  const float* fcb  = (const float*)d_in[14];
  float* outp = (float*)d_out;

  float* ws   = (float*)d_ws;
  float* xp   = ws;                                  // 2048*768
  float* gout = xp   + (size_t)Mm*768;               // 2048*256
  float* q    = gout + (size_t)Mm*Hh;
  float* k    = q    + (size_t)Mm*Hh;
  float* ctx  = k    + (size_t)Mm*Hh;
  u64*  hpair = (u64*)(ctx + (size_t)Mm*Hh);         // 4 batches * 4 slots * 256 = 32 KB
  u16* comb = (u16*)(hpair + 4096);                  // 2048*512 bf16
  u16* Wb   = comb + (size_t)Mm*512;                 // 32000*512 bf16

  hipMemsetAsync(hpair, 0, 4096*sizeof(u64), stream);

  dim3 g1(Mm/32, 768/64);
  gemm_small<true><<<g1, 256, 0, stream>>>(embW, x, wih, bih, xp, 768);

  // gru_scan also performs the fcW->bf16 conversion on its idle blocks
  gru_scan<<<64, 512, 0, stream>>>(xp, h0, whh, bhh, gout, hpair, fcW, Wb);

  dim3 g3(Mm/32, 256/64);
  gemm_small<false><<<g3, 256, 0, stream>>>(gout, nullptr, awW, awb, q, 256);
  gemm_small<false><<<g3, 256, 0, stream>>>(gout, nullptr, auW, aub, k, 256);

  attn_kernel<<<Bb*Tt, 256, 0, stream>>>(gout, q, k, avW, avb, ctx);

  conv_comb_bf16<<<512, 256, 0, stream>>>(gout, ctx, comb);

  fc_mfma<<<16*250, 256, 0, stream>>>(comb, Wb, fcb, outp);

  copy_hlast<<<4, 256, 0, stream>>>(gout, outp + (size_t)Mm*Vv);
}